// Round 2
// baseline (301.947 us; speedup 1.0000x reference)
//
#include <hip/hip_runtime.h>
#include <hip/hip_bf16.h>

#define D 256

typedef __attribute__((ext_vector_type(8))) short bf16x8;
typedef __attribute__((ext_vector_type(4))) float f32x4;

__device__ __forceinline__ unsigned short f2bf(float a) {
    unsigned int u = __float_as_uint(a);
    u = (u + 0x7fffu + ((u >> 16) & 1u)) >> 16;
    return (unsigned short)u;
}

// one v_cvt_pk_bf16_f32: D.lo = bf16(a), D.hi = bf16(b)
__device__ __forceinline__ unsigned int cvt_pk_bf16(float a, float b) {
    unsigned int r;
    asm("v_cvt_pk_bf16_f32 %0, %1, %2" : "=v"(r) : "v"(a), "v"(b));
    return r;
}

// branch-free tanh via v_exp_f32 + v_rcp_f32 (rel err ~1e-6)
__device__ __forceinline__ float fast_tanh(float v) {
    float a = __builtin_fabsf(v);
    float e = __builtin_amdgcn_exp2f(a * -2.88539008177793f);   // exp(-2a)
    float t = (1.0f - e) * __builtin_amdgcn_rcpf(1.0f + e);
    return __builtin_copysignf(t, v);
}

// ---------------------------------------------------------------------------
// Pack W1 (f32 [256][256], row k, col j) into bf16 MFMA b-frag layout:
// W1p[((kk*16 + cb)*64 + lane)*8 + e] = bf16(W1[(32*kk + 8*(lane>>4) + e)*256 + 16*cb + (lane&15)])
// ---------------------------------------------------------------------------
__global__ void pack_w1_k(const float* __restrict__ W1, unsigned short* __restrict__ W1p) {
    int p = blockIdx.x * 256 + threadIdx.x;   // 0 .. 65535
    int e  = p & 7;
    int l  = (p >> 3) & 63;
    int cb = (p >> 9) & 15;
    int kk = p >> 13;
    int k   = 32 * kk + 8 * (l >> 4) + e;
    int col = 16 * cb + (l & 15);
    W1p[p] = f2bf(W1[k * D + col]);
}

// ---------------------------------------------------------------------------
// Zero the accumulation workspace (accb[G*D] followed contiguously by den[G]).
// ---------------------------------------------------------------------------
__global__ void zero_k(float* __restrict__ p, int n) {
    int i = blockIdx.x * 256 + threadIdx.x;
    if (i < n) p[i] = 0.f;
}

// ---------------------------------------------------------------------------
// Fused: scores (bf16 MFMA) -> e=exp(score) -> unnormalized weighted scatter.
//   accb[g,:] += sum_i e_i * x_i   (f32 x held in registers, exact)
//   den[g]    += sum_i e_i
// No per-graph max needed: |score| <= ||W2||_1 + |b2| ~ 13, exp safe in f32.
// Block: 256 threads = 4 waves, 64 rows per block; wave w owns cols [64w,64w+64).
// Output cols processed in TWO sequential halves (acc[4][2] = 32 VGPR) so the
// f32 x register copy (64 VGPR) + acc fits under the 168-VGPR / 3-wave-per-EU
// cap -> 3 blocks/CU instead of 2 (latency hiding was the round-1 limiter).
// ---------------------------------------------------------------------------
__global__ void __launch_bounds__(256, 3)
fused_k(const float* __restrict__ x,
        const unsigned short* __restrict__ W1p,
        const float* __restrict__ b1,
        const float* __restrict__ W2,
        const float* __restrict__ b2,
        const int* __restrict__ batch, int N,
        float* __restrict__ accb, float* __restrict__ den) {
    __shared__ __align__(16) unsigned int Xl[64 * 128];  // 64 rows x 512B (bf16), XOR-swizzled
    __shared__ float scpart[4][64];
    __shared__ float red[4][256];
    __shared__ float erow[64];
    __shared__ int   bids[64];

    const int tid = threadIdx.x;
    const int w   = tid >> 6;       // wave id 0..3
    const int l   = tid & 63;       // lane in wave
    const int l15 = l & 15;
    const int g4  = l >> 4;         // 0..3
    const int row0 = blockIdx.x * 64;

    // ---- stage X tile into LDS as bf16 (swizzled) AND keep f32 copy in regs ----
    // thread (w,l): rows r = 4*it + w, float4 column chunk l (cols 4l..4l+3)
    float4 xv[16];
    const float4* x4 = reinterpret_cast<const float4*>(x);
    if (row0 + 64 <= N) {
        #pragma unroll
        for (int it = 0; it < 16; ++it) {
            int r = 4 * it + w;
            float4 v = x4[(size_t)(row0 + r) * 64 + l];
            xv[it] = v;
            unsigned int lo = cvt_pk_bf16(v.x, v.y);
            unsigned int hi = cvt_pk_bf16(v.z, v.w);
            int uidx = r * 128 + ((l * 2) ^ ((r & 7) << 2));
            *reinterpret_cast<uint2*>(&Xl[uidx]) = make_uint2(lo, hi);
        }
    } else {
        #pragma unroll
        for (int it = 0; it < 16; ++it) {
            int r = 4 * it + w;
            float4 v = make_float4(0.f, 0.f, 0.f, 0.f);
            if (row0 + r < N) v = x4[(size_t)(row0 + r) * 64 + l];
            xv[it] = v;
            unsigned int lo = cvt_pk_bf16(v.x, v.y);
            unsigned int hi = cvt_pk_bf16(v.z, v.w);
            int uidx = r * 128 + ((l * 2) ^ ((r & 7) << 2));
            *reinterpret_cast<uint2*>(&Xl[uidx]) = make_uint2(lo, hi);
        }
    }
    if (tid < 64) bids[tid] = batch[min(row0 + tid, N - 1)];
    __syncthreads();

    // ---- MFMA + epilogue, two column-halves to cap register pressure ----
    float part[4][4];
    #pragma unroll
    for (int m = 0; m < 4; ++m)
        #pragma unroll
        for (int r = 0; r < 4; ++r) part[m][r] = 0.f;

    #pragma unroll
    for (int h = 0; h < 2; ++h) {
        f32x4 acc[4][2];
        #pragma unroll
        for (int m = 0; m < 4; ++m)
            #pragma unroll
            for (int n = 0; n < 2; ++n)
                acc[m][n] = (f32x4){0.f, 0.f, 0.f, 0.f};

        #pragma unroll
        for (int kk = 0; kk < 8; ++kk) {
            bf16x8 bfr[2];
            #pragma unroll
            for (int n = 0; n < 2; ++n) {
                const bf16x8* bp = reinterpret_cast<const bf16x8*>(
                    W1p + (size_t)(((kk * 16) + (w * 4 + 2 * h + n)) * 64 + l) * 8);
                bfr[n] = *bp;
            }
            bf16x8 afr[4];
            #pragma unroll
            for (int m = 0; m < 4; ++m) {
                int r = 16 * m + l15;
                int cbyte = 64 * kk + 16 * g4;
                int uidx = r * 128 + (((cbyte >> 2)) ^ ((r & 7) << 2));
                afr[m] = *reinterpret_cast<const bf16x8*>(&Xl[uidx]);
            }
            #pragma unroll
            for (int m = 0; m < 4; ++m)
                #pragma unroll
                for (int n = 0; n < 2; ++n)
                    acc[m][n] = __builtin_amdgcn_mfma_f32_16x16x32_bf16(afr[m], bfr[n], acc[m][n], 0, 0, 0);
        }

        // epilogue for this half: +b1, fast_tanh, *W2, accumulate into part
        #pragma unroll
        for (int n = 0; n < 2; ++n) {
            int col = 64 * w + 16 * (2 * h + n) + l15;
            float b1v = b1[col];
            float w2v = W2[col];
            #pragma unroll
            for (int m = 0; m < 4; ++m)
                #pragma unroll
                for (int r = 0; r < 4; ++r) {
                    float hh = fast_tanh(acc[m][n][r] + b1v);
                    part[m][r] += hh * w2v;
                }
        }
    }

    #pragma unroll
    for (int m = 0; m < 4; ++m)
        #pragma unroll
        for (int r = 0; r < 4; ++r) {
            float p = part[m][r];
            p += __shfl_xor(p, 8, 16);
            p += __shfl_xor(p, 4, 16);
            p += __shfl_xor(p, 2, 16);
            p += __shfl_xor(p, 1, 16);
            if (l15 == 0) scpart[w][16 * m + 4 * g4 + r] = p;
        }
    __syncthreads();

    if (tid < 64) {
        float s = scpart[0][tid] + scpart[1][tid] + scpart[2][tid] + scpart[3][tid] + b2[0];
        erow[tid] = (row0 + tid < N)
                  ? __builtin_amdgcn_exp2f(s * 1.4426950408889634f)
                  : 0.f;
    }
    __syncthreads();

    // ---- pooling: per graph in this block's row range, scatter-add ----
    const int g0 = bids[0], g1 = bids[63];
    for (int g = g0; g <= g1; ++g) {
        float4 a = make_float4(0.f, 0.f, 0.f, 0.f);
        #pragma unroll
        for (int it = 0; it < 16; ++it) {
            int r = 4 * it + w;
            float e = (bids[r] == g) ? erow[r] : 0.f;
            a.x += e * xv[it].x;
            a.y += e * xv[it].y;
            a.z += e * xv[it].z;
            a.w += e * xv[it].w;
        }
        red[w][l * 4 + 0] = a.x;
        red[w][l * 4 + 1] = a.y;
        red[w][l * 4 + 2] = a.z;
        red[w][l * 4 + 3] = a.w;
        __syncthreads();
        float s = red[0][tid] + red[1][tid] + red[2][tid] + red[3][tid];
        atomicAdd(&accb[(size_t)g * D + tid], s);
        if (w == 0) {
            float e = (bids[l] == g) ? erow[l] : 0.f;
            e += __shfl_xor(e, 32);
            e += __shfl_xor(e, 16);
            e += __shfl_xor(e, 8);
            e += __shfl_xor(e, 4);
            e += __shfl_xor(e, 2);
            e += __shfl_xor(e, 1);
            if (l == 0) atomicAdd(&den[g], e);
        }
        __syncthreads();   // red reused next g
    }
}

// ---------------------------------------------------------------------------
// out[g,:] = accb[g,:] / den[g]   (empty graph -> 0, matches reference)
// ---------------------------------------------------------------------------
__global__ void __launch_bounds__(256)
norm_k(const float* __restrict__ accb, const float* __restrict__ den,
       float* __restrict__ out) {
    int g = blockIdx.x;
    float dv = den[g];
    float inv = (dv > 0.f) ? 1.0f / dv : 0.f;
    out[(size_t)g * D + threadIdx.x] = accb[(size_t)g * D + threadIdx.x] * inv;
}

// ---------------------------------------------------------------------------
extern "C" void kernel_launch(void* const* d_in, const int* in_sizes, int n_in,
                              void* d_out, int out_size, void* d_ws, size_t ws_size,
                              hipStream_t stream) {
    const float* x     = (const float*)d_in[0];
    const int*   batch = (const int*)d_in[1];
    const float* W1    = (const float*)d_in[3];
    const float* b1    = (const float*)d_in[4];
    const float* W2    = (const float*)d_in[5];
    const float* b2    = (const float*)d_in[6];
    float* out = (float*)d_out;

    const int N = in_sizes[0] / D;
    const int G = out_size / D;

    char* ws = (char*)d_ws;
    unsigned short* W1p = (unsigned short*)ws;               // 128 KB
    float* accb = (float*)(ws + 131072);                     // G*D*4 bytes
    float* den  = (float*)(ws + 131072 + (size_t)G * D * 4); // G*4 bytes (contiguous after accb)

    zero_k<<<dim3((G * D + G + 255) / 256), dim3(256), 0, stream>>>(accb, G * D + G);
    pack_w1_k<<<dim3(256), dim3(256), 0, stream>>>(W1, W1p);
    fused_k<<<dim3((N + 63) / 64), dim3(256), 0, stream>>>(x, W1p, b1, W2, b2, batch, N, accb, den);
    norm_k<<<dim3(G), dim3(256), 0, stream>>>(accb, den, out);
}

// Round 3
// 226.681 us; speedup vs baseline: 1.3320x; 1.3320x over previous
//
#include <hip/hip_runtime.h>
#include <hip/hip_bf16.h>

#define D 256

typedef __attribute__((ext_vector_type(8))) short bf16x8;
typedef __attribute__((ext_vector_type(4))) float f32x4;

__device__ __forceinline__ unsigned short f2bf(float a) {
    unsigned int u = __float_as_uint(a);
    u = (u + 0x7fffu + ((u >> 16) & 1u)) >> 16;
    return (unsigned short)u;
}

// one v_cvt_pk_bf16_f32: D.lo = bf16(a), D.hi = bf16(b)
__device__ __forceinline__ unsigned int cvt_pk_bf16(float a, float b) {
    unsigned int r;
    asm("v_cvt_pk_bf16_f32 %0, %1, %2" : "=v"(r) : "v"(a), "v"(b));
    return r;
}

// branch-free tanh via v_exp_f32 + v_rcp_f32 (rel err ~1e-6)
__device__ __forceinline__ float fast_tanh(float v) {
    float a = __builtin_fabsf(v);
    float e = __builtin_amdgcn_exp2f(a * -2.88539008177793f);   // exp(-2a)
    float t = (1.0f - e) * __builtin_amdgcn_rcpf(1.0f + e);
    return __builtin_copysignf(t, v);
}

// ---------------------------------------------------------------------------
// Swizzled byte offset into the f32 x-tile (k-major transposed):
//   chunk c = k/8 (0..31), row r (0..31), 16B-half q (0..1)
// Base = c*1024 + r*32 + q*16; XOR (c&3)<<5 spreads staging/pooling lanes
// (c varies) across banks; XOR (r&4)<<2 spreads MFMA A-frag lanes (r varies).
// Bijective; conflict-free per 8-lane subphase for all three access patterns.
// ---------------------------------------------------------------------------
__device__ __forceinline__ int xf_off(int c, int r, int q) {
    return ((c << 10) + (r << 5) + (q << 4)) ^ ((c & 3) << 5) ^ ((r & 4) << 2);
}

// ---------------------------------------------------------------------------
// Pack W1 (f32 [256][256], row k, col j) into bf16 MFMA b-frag layout:
// W1p[((kk*16 + cb)*64 + lane)*8 + e] = bf16(W1[(32*kk + 8*(lane>>4) + e)*256 + 16*cb + (lane&15)])
// ---------------------------------------------------------------------------
__global__ void pack_w1_k(const float* __restrict__ W1, unsigned short* __restrict__ W1p) {
    int p = blockIdx.x * 256 + threadIdx.x;   // 0 .. 65535
    int e  = p & 7;
    int l  = (p >> 3) & 63;
    int cb = (p >> 9) & 15;
    int kk = p >> 13;
    int k   = 32 * kk + 8 * (l >> 4) + e;
    int col = 16 * cb + (l & 15);
    W1p[p] = f2bf(W1[k * D + col]);
}

// ---------------------------------------------------------------------------
// Zero the accumulation workspace (accb[G*D] followed contiguously by den[G]).
// ---------------------------------------------------------------------------
__global__ void zero_k(float* __restrict__ p, int n) {
    int i = blockIdx.x * 256 + threadIdx.x;
    if (i < n) p[i] = 0.f;
}

// ---------------------------------------------------------------------------
// Fused: scores (bf16 MFMA) -> e=exp(score) -> unnormalized weighted scatter.
//   accb[g,:] += sum_i e_i * x_i ; den[g] += sum_i e_i   (f32 x from LDS, exact)
// No per-graph max needed: |score| <= ||W2||_1 + |b2| ~ 13, exp safe in f32.
// 32 rows/block, 256 threads = 4 waves; wave w owns cols [64w, 64w+64).
// f32 x tile lives in LDS (32 KB, swizzled); bf16 A-frags are cvt'd on the fly.
// No big register arrays -> ~110 VGPR -> 4 blocks/CU (round-2 spill fixed).
// ---------------------------------------------------------------------------
__global__ void __launch_bounds__(256, 4)
fused_k(const float* __restrict__ x,
        const unsigned short* __restrict__ W1p,
        const float* __restrict__ b1,
        const float* __restrict__ W2,
        const float* __restrict__ b2,
        const int* __restrict__ batch, int N,
        float* __restrict__ accb, float* __restrict__ den) {
    __shared__ __align__(16) float Xf[8192];    // 32 KB swizzled f32 tile
    __shared__ float red[4][256];
    __shared__ float scpart[4][32];
    __shared__ float erow[32];
    __shared__ int   bids[32];

    const int tid = threadIdx.x;
    const int w   = tid >> 6;       // wave id 0..3
    const int l   = tid & 63;       // lane in wave
    const int l15 = l & 15;
    const int g4  = l >> 4;         // 0..3
    const int row0 = blockIdx.x * 32;

    char* xb = reinterpret_cast<char*>(Xf);

    // ---- stage X tile (32 x 256 f32) into swizzled LDS ----
    // iteration it: 256 consecutive 16B-chunks; idx -> row r = idx>>6, col4 = idx&63
    const float4* x4 = reinterpret_cast<const float4*>(x);
    const bool full = (row0 + 32 <= N);
    #pragma unroll
    for (int it = 0; it < 8; ++it) {
        int idx = it * 256 + tid;            // 0..2047
        int r    = idx >> 6;
        int col4 = idx & 63;
        float4 v = make_float4(0.f, 0.f, 0.f, 0.f);
        if (full || row0 + r < N) v = x4[(size_t)(row0 + r) * 64 + col4];
        *reinterpret_cast<float4*>(xb + xf_off(col4 >> 1, r, col4 & 1)) = v;
    }
    if (tid < 32) bids[tid] = batch[min(row0 + tid, N - 1)];
    __syncthreads();

    // ---- MFMA: scores = tanh(x@W1 + b1) @ W2 + b2 ----
    f32x4 acc[2][4];
    #pragma unroll
    for (int m = 0; m < 2; ++m)
        #pragma unroll
        for (int n = 0; n < 4; ++n)
            acc[m][n] = (f32x4){0.f, 0.f, 0.f, 0.f};

    #pragma unroll
    for (int kk = 0; kk < 8; ++kk) {
        bf16x8 bfr[4];
        #pragma unroll
        for (int n = 0; n < 4; ++n) {
            const bf16x8* bp = reinterpret_cast<const bf16x8*>(
                W1p + (size_t)(((kk * 16) + (w * 4 + n)) * 64 + l) * 8);
            bfr[n] = *bp;
        }
        bf16x8 afr[2];
        #pragma unroll
        for (int m = 0; m < 2; ++m) {
            int r = 16 * m + l15;
            int c = 4 * kk + g4;
            int o0 = xf_off(c, r, 0);
            float4 f0 = *reinterpret_cast<const float4*>(xb + o0);
            float4 f1 = *reinterpret_cast<const float4*>(xb + (o0 ^ 16));
            uint4 u;
            u.x = cvt_pk_bf16(f0.x, f0.y);
            u.y = cvt_pk_bf16(f0.z, f0.w);
            u.z = cvt_pk_bf16(f1.x, f1.y);
            u.w = cvt_pk_bf16(f1.z, f1.w);
            afr[m] = *reinterpret_cast<bf16x8*>(&u);
        }
        #pragma unroll
        for (int m = 0; m < 2; ++m)
            #pragma unroll
            for (int n = 0; n < 4; ++n)
                acc[m][n] = __builtin_amdgcn_mfma_f32_16x16x32_bf16(afr[m], bfr[n], acc[m][n], 0, 0, 0);
    }

    // ---- epilogue: +b1, fast_tanh, *W2, reduce over cols -> per-row score ----
    float part[2][4];
    #pragma unroll
    for (int m = 0; m < 2; ++m)
        #pragma unroll
        for (int r = 0; r < 4; ++r) part[m][r] = 0.f;

    #pragma unroll
    for (int n = 0; n < 4; ++n) {
        int col = 64 * w + 16 * n + l15;
        float b1v = b1[col];
        float w2v = W2[col];
        #pragma unroll
        for (int m = 0; m < 2; ++m)
            #pragma unroll
            for (int r = 0; r < 4; ++r) {
                float h = fast_tanh(acc[m][n][r] + b1v);
                part[m][r] += h * w2v;
            }
    }

    #pragma unroll
    for (int m = 0; m < 2; ++m)
        #pragma unroll
        for (int r = 0; r < 4; ++r) {
            float p = part[m][r];
            p += __shfl_xor(p, 8, 16);
            p += __shfl_xor(p, 4, 16);
            p += __shfl_xor(p, 2, 16);
            p += __shfl_xor(p, 1, 16);
            if (l15 == 0) scpart[w][16 * m + 4 * g4 + r] = p;
        }
    __syncthreads();

    if (tid < 32) {
        float s = scpart[0][tid] + scpart[1][tid] + scpart[2][tid] + scpart[3][tid] + b2[0];
        erow[tid] = (row0 + tid < N)
                  ? __builtin_amdgcn_exp2f(s * 1.4426950408889634f)
                  : 0.f;
    }
    __syncthreads();

    // ---- pooling: per graph in this block's row range, scatter-add ----
    const int g0 = bids[0], g1 = bids[31];
    const int pc = l >> 1;          // chunk for pooling reads
    const int pq = l & 1;           // half
    for (int g = g0; g <= g1; ++g) {
        float4 a = make_float4(0.f, 0.f, 0.f, 0.f);
        #pragma unroll
        for (int it = 0; it < 8; ++it) {
            int r = 4 * it + w;
            float e = (bids[r] == g) ? erow[r] : 0.f;
            float4 v = *reinterpret_cast<const float4*>(xb + xf_off(pc, r, pq));
            a.x += e * v.x;
            a.y += e * v.y;
            a.z += e * v.z;
            a.w += e * v.w;
        }
        red[w][l * 4 + 0] = a.x;
        red[w][l * 4 + 1] = a.y;
        red[w][l * 4 + 2] = a.z;
        red[w][l * 4 + 3] = a.w;
        __syncthreads();
        float s = red[0][tid] + red[1][tid] + red[2][tid] + red[3][tid];
        atomicAdd(&accb[(size_t)g * D + tid], s);
        if (w == 0) {
            float e = 0.f;
            if (l < 32) e = (bids[l] == g) ? erow[l] : 0.f;
            e += __shfl_xor(e, 32);
            e += __shfl_xor(e, 16);
            e += __shfl_xor(e, 8);
            e += __shfl_xor(e, 4);
            e += __shfl_xor(e, 2);
            e += __shfl_xor(e, 1);
            if (l == 0) atomicAdd(&den[g], e);
        }
        __syncthreads();   // red reused next g
    }
}

// ---------------------------------------------------------------------------
// out[g,:] = accb[g,:] / den[g]   (empty graph -> 0, matches reference)
// ---------------------------------------------------------------------------
__global__ void __launch_bounds__(256)
norm_k(const float* __restrict__ accb, const float* __restrict__ den,
       float* __restrict__ out) {
    int g = blockIdx.x;
    float dv = den[g];
    float inv = (dv > 0.f) ? 1.0f / dv : 0.f;
    out[(size_t)g * D + threadIdx.x] = accb[(size_t)g * D + threadIdx.x] * inv;
}

// ---------------------------------------------------------------------------
extern "C" void kernel_launch(void* const* d_in, const int* in_sizes, int n_in,
                              void* d_out, int out_size, void* d_ws, size_t ws_size,
                              hipStream_t stream) {
    const float* x     = (const float*)d_in[0];
    const int*   batch = (const int*)d_in[1];
    const float* W1    = (const float*)d_in[3];
    const float* b1    = (const float*)d_in[4];
    const float* W2    = (const float*)d_in[5];
    const float* b2    = (const float*)d_in[6];
    float* out = (float*)d_out;

    const int N = in_sizes[0] / D;
    const int G = out_size / D;

    char* ws = (char*)d_ws;
    unsigned short* W1p = (unsigned short*)ws;               // 128 KB
    float* accb = (float*)(ws + 131072);                     // G*D*4 bytes
    float* den  = (float*)(ws + 131072 + (size_t)G * D * 4); // G*4 bytes (contiguous after accb)

    zero_k<<<dim3((G * D + G + 255) / 256), dim3(256), 0, stream>>>(accb, G * D + G);
    pack_w1_k<<<dim3(256), dim3(256), 0, stream>>>(W1, W1p);
    fused_k<<<dim3((N + 31) / 32), dim3(256), 0, stream>>>(x, W1p, b1, W2, b2, batch, N, accb, den);
    norm_k<<<dim3(G), dim3(256), 0, stream>>>(accb, den, out);
}

// Round 5
// 189.174 us; speedup vs baseline: 1.5961x; 1.1983x over previous
//
#include <hip/hip_runtime.h>

#define D 256
#define ROWS 32
#define NBLK 512

typedef __attribute__((ext_vector_type(8))) short bf16x8;
typedef __attribute__((ext_vector_type(4))) float f32x4;

__device__ __forceinline__ unsigned short f2bf(float a) {
    unsigned int u = __float_as_uint(a);
    u = (u + 0x7fffu + ((u >> 16) & 1u)) >> 16;
    return (unsigned short)u;
}

__device__ __forceinline__ unsigned int cvt_pk_bf16(float a, float b) {
    unsigned int r;
    asm("v_cvt_pk_bf16_f32 %0, %1, %2" : "=v"(r) : "v"(a), "v"(b));
    return r;
}

__device__ __forceinline__ float fast_tanh(float v) {
    float a = __builtin_fabsf(v);
    float e = __builtin_amdgcn_exp2f(a * -2.88539008177793f);   // exp(-2a)
    float t = (1.0f - e) * __builtin_amdgcn_rcpf(1.0f + e);
    return __builtin_copysignf(t, v);
}

// Swizzled byte offset into a 32-row f32 x-tile (k-major transposed):
// chunk c = col8 (0..31), row r (0..31), 16B-half q (0..1).
__device__ __forceinline__ int xf_off(int c, int r, int q) {
    return ((c << 10) + (r << 5) + (q << 4)) ^ ((c & 3) << 5) ^ ((r & 4) << 2);
}

__device__ __forceinline__ void gload_lds16(const void* g, void* l) {
    __builtin_amdgcn_global_load_lds(
        (const __attribute__((address_space(1))) unsigned int*)g,
        (__attribute__((address_space(3))) unsigned int*)l, 16, 0, 0);
}

// ---------------------------------------------------------------------------
__global__ void pack_w1_k(const float* __restrict__ W1, unsigned short* __restrict__ W1p) {
    int p = blockIdx.x * 256 + threadIdx.x;   // 0 .. 65535
    int e  = p & 7;
    int l  = (p >> 3) & 63;
    int cb = (p >> 9) & 15;
    int kk = p >> 13;
    int k   = 32 * kk + 8 * (l >> 4) + e;
    int col = 16 * cb + (l & 15);
    W1p[p] = f2bf(W1[k * D + col]);
}

__global__ void zero_k(float* __restrict__ p, int n) {
    int i = blockIdx.x * 256 + threadIdx.x;
    if (i < n) p[i] = 0.f;
}

// ---------------------------------------------------------------------------
// STAGE: async global->LDS of one 32x256 f32 tile, linear LDS dest,
// inverse-swizzled per-lane global source (so swizzled reads see x[r][8c..]).
#define STAGE(XN, tn) do {                                                      \
    const int _r0s = (tn) * ROWS;                                               \
    _Pragma("unroll")                                                           \
    for (int _it = 0; _it < 8; ++_it) {                                         \
        const int _c = _it * 4 + w;                                             \
        const int _r = (l >> 1) ^ (_c & 3);                                     \
        const int _q = (l & 1) ^ ((_r >> 2) & 1);                               \
        int _row = _r0s + _r; _row = (_row < N) ? _row : (N - 1);               \
        gload_lds16((const char*)x + ((size_t)_row << 10) + (size_t)(((_c << 1) + _q) << 4), \
                    (char*)(XN) + (_it << 12) + (w << 10) + (l << 4));          \
    }                                                                           \
} while (0)

// FLUSHX: emit accumulated (a4, den_p) for g_cur; compute next graph id -> gnv.
#define FLUSHX() do {                                                           \
    *reinterpret_cast<float4*>(&red[w][l * 4]) = a4;                            \
    int _m8 = 0x7fffffff;                                                       \
    _Pragma("unroll")                                                           \
    for (int _it = 0; _it < 8; ++_it)                                           \
        if (bg[_it] > g_cur && bg[_it] < _m8) _m8 = bg[_it];                    \
    _m8 = min(_m8, __shfl_xor(_m8, 1));  _m8 = min(_m8, __shfl_xor(_m8, 2));    \
    _m8 = min(_m8, __shfl_xor(_m8, 4));  _m8 = min(_m8, __shfl_xor(_m8, 8));    \
    _m8 = min(_m8, __shfl_xor(_m8, 16)); _m8 = min(_m8, __shfl_xor(_m8, 32));   \
    float _dw = den_p;                                                          \
    _dw += __shfl_xor(_dw, 1);  _dw += __shfl_xor(_dw, 2);                      \
    _dw += __shfl_xor(_dw, 4);  _dw += __shfl_xor(_dw, 8);                      \
    _dw += __shfl_xor(_dw, 16); _dw += __shfl_xor(_dw, 32);                     \
    if (l == 0) { gmin4[w] = _m8; denw[w] = _dw; }                              \
    asm volatile("s_waitcnt lgkmcnt(0)" ::: "memory");                          \
    __builtin_amdgcn_sched_barrier(0);                                          \
    __builtin_amdgcn_s_barrier();                                               \
    __builtin_amdgcn_sched_barrier(0);                                          \
    { const float _fs = red[0][tid] + red[1][tid] + red[2][tid] + red[3][tid];  \
      atomicAdd(&accb[(size_t)g_cur * D + tid], _fs); }                         \
    if (tid == 0)                                                               \
        atomicAdd(&den[g_cur], (denw[0] + denw[1] + denw[2] + denw[3]) * 0.015625f); \
    gnv = min(min(gmin4[0], gmin4[1]), min(gmin4[2], gmin4[3]));                \
    a4 = make_float4(0.f, 0.f, 0.f, 0.f); den_p = 0.f;                          \
    __builtin_amdgcn_s_barrier();                                               \
    __builtin_amdgcn_sched_barrier(0);                                          \
} while (0)

// POOL: accumulate this tile's rows into (a4, den_p), flushing on graph change.
// Each row r is accumulated by the 64 lanes of wave r%4 -> den scaled by 1/64.
#define POOL(XC) do {                                                           \
    if (g_cur < 0) g_cur = g0u;                                                 \
    while (true) {                                                              \
        _Pragma("unroll")                                                       \
        for (int _it = 0; _it < 8; ++_it) {                                     \
            const int _r = 4 * _it + w;                                         \
            const float _e = (bg[_it] == g_cur) ? erow[_r] : 0.f;               \
            const float4 _v = *reinterpret_cast<const float4*>(                 \
                (const char*)(XC) + xf_off(l >> 1, _r, l & 1));                 \
            a4.x += _e * _v.x; a4.y += _e * _v.y;                               \
            a4.z += _e * _v.z; a4.w += _e * _v.w;                               \
            den_p += _e;                                                        \
        }                                                                       \
        if (glast <= g_cur) break;                                              \
        FLUSHX();                                                               \
        g_cur = gnv;                                                            \
    }                                                                           \
} while (0)

// BODY: process tile t from XC, prefetch tile t+1 into XN. ++t at end.
#define BODY(XC, XN) do {                                                       \
    const int _row0 = t * ROWS;                                                 \
    _Pragma("unroll")                                                           \
    for (int _it = 0; _it < 8; ++_it) {                                         \
        int _ri = _row0 + 4 * _it + w;                                          \
        bg[_it] = batch[_ri < N ? _ri : N - 1];                                 \
    }                                                                           \
    const int g0u = batch[_row0];                                               \
    int _gli = _row0 + 31;                                                      \
    const int glast = batch[_gli < N ? _gli : N - 1];                           \
    __builtin_amdgcn_sched_barrier(0);                                          \
    const bool _hn = (t + 1 < t1);                                              \
    if (_hn) {                                                                  \
        STAGE(XN, t + 1);                                                       \
        asm volatile("s_waitcnt vmcnt(8) lgkmcnt(0)" ::: "memory");             \
    } else {                                                                    \
        asm volatile("s_waitcnt vmcnt(0) lgkmcnt(0)" ::: "memory");             \
    }                                                                           \
    __builtin_amdgcn_sched_barrier(0);                                          \
    __builtin_amdgcn_s_barrier();                                               \
    __builtin_amdgcn_sched_barrier(0);                                          \
    /* ---- scores: tanh(x@W1+b1)@W2+b2 via MFMA, A from XC, B from regs ---- */ \
    f32x4 acc[2][4];                                                            \
    _Pragma("unroll")                                                           \
    for (int _m = 0; _m < 2; ++_m)                                              \
        _Pragma("unroll")                                                       \
        for (int _n = 0; _n < 4; ++_n) acc[_m][_n] = (f32x4){0.f, 0.f, 0.f, 0.f}; \
    _Pragma("unroll")                                                           \
    for (int _kk = 0; _kk < 8; ++_kk) {                                         \
        bf16x8 _afr[2];                                                         \
        _Pragma("unroll")                                                       \
        for (int _m = 0; _m < 2; ++_m) {                                        \
            const int _rr = 16 * _m + l15;                                      \
            const int _cc = 4 * _kk + g4;                                       \
            const int _o0 = xf_off(_cc, _rr, 0);                                \
            const float4 _f0 = *reinterpret_cast<const float4*>((const char*)(XC) + _o0); \
            const float4 _f1 = *reinterpret_cast<const float4*>((const char*)(XC) + (_o0 ^ 16)); \
            uint4 _u;                                                           \
            _u.x = cvt_pk_bf16(_f0.x, _f0.y); _u.y = cvt_pk_bf16(_f0.z, _f0.w); \
            _u.z = cvt_pk_bf16(_f1.x, _f1.y); _u.w = cvt_pk_bf16(_f1.z, _f1.w); \
            _afr[_m] = *reinterpret_cast<bf16x8*>(&_u);                         \
        }                                                                       \
        _Pragma("unroll")                                                       \
        for (int _m = 0; _m < 2; ++_m)                                          \
            _Pragma("unroll")                                                   \
            for (int _n = 0; _n < 4; ++_n)                                      \
                acc[_m][_n] = __builtin_amdgcn_mfma_f32_16x16x32_bf16(          \
                    _afr[_m], bfr[_kk * 4 + _n], acc[_m][_n], 0, 0, 0);         \
    }                                                                           \
    {                                                                           \
        float _part[2][4];                                                      \
        _Pragma("unroll")                                                       \
        for (int _m = 0; _m < 2; ++_m)                                          \
            _Pragma("unroll")                                                   \
            for (int _r = 0; _r < 4; ++_r) _part[_m][_r] = 0.f;                 \
        _Pragma("unroll")                                                       \
        for (int _n = 0; _n < 4; ++_n)                                          \
            _Pragma("unroll")                                                   \
            for (int _m = 0; _m < 2; ++_m)                                      \
                _Pragma("unroll")                                               \
                for (int _r = 0; _r < 4; ++_r) {                                \
                    float _h = fast_tanh(acc[_m][_n][_r] + b1v[_n]);            \
                    _part[_m][_r] += _h * w2v[_n];                              \
                }                                                               \
        _Pragma("unroll")                                                       \
        for (int _m = 0; _m < 2; ++_m)                                          \
            _Pragma("unroll")                                                   \
            for (int _r = 0; _r < 4; ++_r) {                                    \
                float _p = _part[_m][_r];                                       \
                _p += __shfl_xor(_p, 8, 16); _p += __shfl_xor(_p, 4, 16);       \
                _p += __shfl_xor(_p, 2, 16); _p += __shfl_xor(_p, 1, 16);       \
                if (l15 == 0) scpart[w][16 * _m + 4 * g4 + _r] = _p;            \
            }                                                                   \
    }                                                                           \
    asm volatile("s_waitcnt lgkmcnt(0)" ::: "memory");                          \
    __builtin_amdgcn_sched_barrier(0);                                          \
    __builtin_amdgcn_s_barrier();                                               \
    __builtin_amdgcn_sched_barrier(0);                                          \
    if (tid < 32) {                                                             \
        float _s = scpart[0][tid] + scpart[1][tid] + scpart[2][tid] + scpart[3][tid] + b2v; \
        erow[tid] = ((_row0 + tid) < N)                                         \
                  ? __builtin_amdgcn_exp2f(_s * 1.4426950408889634f) : 0.f;     \
    }                                                                           \
    asm volatile("s_waitcnt lgkmcnt(0)" ::: "memory");                          \
    __builtin_amdgcn_sched_barrier(0);                                          \
    __builtin_amdgcn_s_barrier();                                               \
    __builtin_amdgcn_sched_barrier(0);                                          \
    POOL(XC);                                                                   \
    asm volatile("s_waitcnt lgkmcnt(0)" ::: "memory");                          \
    __builtin_amdgcn_sched_barrier(0);                                          \
    __builtin_amdgcn_s_barrier();                                               \
    __builtin_amdgcn_sched_barrier(0);                                          \
    ++t;                                                                        \
} while (0)

// ---------------------------------------------------------------------------
// Persistent fused kernel: per block, a contiguous range of 32-row tiles.
// Double-buffered async staging (global_load_lds, counted vmcnt), W1p quarter
// cached in 128 VGPRs, register-resident pooling flushed on graph change.
// ---------------------------------------------------------------------------
__global__ void __launch_bounds__(256, 2)
fused_k(const float* __restrict__ x,
        const unsigned short* __restrict__ W1p,
        const float* __restrict__ b1,
        const float* __restrict__ W2,
        const float* __restrict__ b2,
        const int* __restrict__ batch,
        int N, int NT,
        float* __restrict__ accb, float* __restrict__ den) {
    __shared__ __align__(16) char Xf0[32768];
    __shared__ __align__(16) char Xf1[32768];
    __shared__ __align__(16) float red[4][256];
    __shared__ float scpart[4][32];
    __shared__ float erow[32];
    __shared__ int   gmin4[4];
    __shared__ float denw[4];

    const int tid = threadIdx.x;
    const int w   = tid >> 6;
    const int l   = tid & 63;
    const int l15 = l & 15;
    const int g4  = l >> 4;

    const int tpb = (NT + NBLK - 1) / NBLK;
    int t = blockIdx.x * tpb;
    const int t1 = min(NT, t + tpb);
    if (t >= t1) return;

    // cache this wave's W1p quarter (cols 64w..64w+63): 32 x bf16x8 = 128 VGPR
    bf16x8 bfr[32];
    #pragma unroll
    for (int kk = 0; kk < 8; ++kk)
        #pragma unroll
        for (int n = 0; n < 4; ++n)
            bfr[kk * 4 + n] = *reinterpret_cast<const bf16x8*>(
                W1p + (size_t)(((kk * 16) + (w * 4 + n)) * 64 + l) * 8);

    float b1v[4], w2v[4];
    #pragma unroll
    for (int n = 0; n < 4; ++n) {
        int col = 64 * w + 16 * n + l15;
        b1v[n] = b1[col];
        w2v[n] = W2[col];
    }
    const float b2v = b2[0];

    // prologue: stage first tile into Xf0
    STAGE(Xf0, t);

    float4 a4 = make_float4(0.f, 0.f, 0.f, 0.f);
    float den_p = 0.f;
    int g_cur = -1;
    int gnv = 0;
    int bg[8];   // per-wave graph ids of this tile's rows (kernel scope: FLUSHX uses it)

    while (true) {
        BODY(Xf0, Xf1);
        if (t >= t1) break;
        BODY(Xf1, Xf0);
        if (t >= t1) break;
    }

    // final flush of the last graph
    FLUSHX();
}

// ---------------------------------------------------------------------------
__global__ void __launch_bounds__(256)
norm_k(const float* __restrict__ accb, const float* __restrict__ den,
       float* __restrict__ out) {
    int g = blockIdx.x;
    float dv = den[g];
    float inv = (dv > 0.f) ? 1.0f / dv : 0.f;
    out[(size_t)g * D + threadIdx.x] = accb[(size_t)g * D + threadIdx.x] * inv;
}

// ---------------------------------------------------------------------------
extern "C" void kernel_launch(void* const* d_in, const int* in_sizes, int n_in,
                              void* d_out, int out_size, void* d_ws, size_t ws_size,
                              hipStream_t stream) {
    const float* x     = (const float*)d_in[0];
    const int*   batch = (const int*)d_in[1];
    const float* W1    = (const float*)d_in[3];
    const float* b1    = (const float*)d_in[4];
    const float* W2    = (const float*)d_in[5];
    const float* b2    = (const float*)d_in[6];
    float* out = (float*)d_out;

    const int N = in_sizes[0] / D;
    const int G = out_size / D;
    const int NT = (N + ROWS - 1) / ROWS;

    char* ws = (char*)d_ws;
    unsigned short* W1p = (unsigned short*)ws;               // 128 KB
    float* accb = (float*)(ws + 131072);                     // G*D*4 bytes
    float* den  = (float*)(ws + 131072 + (size_t)G * D * 4); // G*4, contiguous

    zero_k<<<dim3((G * D + G + 255) / 256), dim3(256), 0, stream>>>(accb, G * D + G);
    pack_w1_k<<<dim3(256), dim3(256), 0, stream>>>(W1, W1p);
    fused_k<<<dim3(min(NBLK, NT)), dim3(256), 0, stream>>>(x, W1p, b1, W2, b2, batch,
                                                           N, NT, accb, den);
    norm_k<<<dim3(G), dim3(256), 0, stream>>>(accb, den, out);
}